// Round 3
// baseline (399.211 us; speedup 1.0000x reference)
//
#include <hip/hip_runtime.h>
#include <cmath>

// Problem constants
#define M_B   8
#define LQ    256
#define N_B   64
#define LR    512
#define COND  64
#define PRED  32
#define DH    128
#define QN    193      // LQ-COND+1
#define KN    417      // (LR-PRED)-COND+1
#define QPAD  256      // per-m padded q rows (8*256 = 2048 total)
#define KPAD  448      // padded kpos (14 chunks of 32)

typedef _Float16 half8 __attribute__((ext_vector_type(8)));
typedef float f32x16 __attribute__((ext_vector_type(16)));

__device__ __forceinline__ f32x16 mfma_f16(half8 a, half8 b, f32x16 c) {
    return __builtin_amdgcn_mfma_f32_32x32x16_f16(a, b, c, 0, 0, 0);
}
__device__ __forceinline__ f32x16 zero16() {
    f32x16 z;
    #pragma unroll
    for (int i = 0; i < 16; i++) z[i] = 0.f;
    return z;
}

#define GLOAD_LDS16(g, l) __builtin_amdgcn_global_load_lds( \
    (const __attribute__((address_space(1))) void*)(g), \
    (__attribute__((address_space(3))) void*)(l), 16, 0, 0)

// ---------------- K0: cumsums, minmax offsets/scales, mc, wsum_k ----------------
__global__ void k0_scan(const float* __restrict__ q, const float* __restrict__ r,
                        float* cs_q, float* cs_r, float* mc,
                        float* q_off, float* q_scale, float* k_off, float* k_scale,
                        const float* __restrict__ mw, const float* __restrict__ mb,
                        const float* __restrict__ kw, float* wsum_k) {
    __shared__ float x[512];
    __shared__ float s[512];
    __shared__ float P[256];
    int b = blockIdx.x, t = threadIdx.x;
    if (b == M_B + N_B) {
        // wsum_k[h] = sum_j kw[h][j]
        if (t < 128) {
            float sm = 0.f;
            for (int j = 0; j < 64; j++) sm += kw[t * 64 + j];
            wsum_k[t] = sm;
        }
        return;
    }
    if (b < M_B) {
        // ---- query row b (len 256) ----
        x[t] = q[b * 256 + t];
        __syncthreads();
        s[t] = x[t];
        __syncthreads();
        for (int off = 1; off < 256; off <<= 1) {
            float v = (t >= off) ? s[t - off] : 0.f;
            __syncthreads();
            s[t] += v;
            __syncthreads();
        }
        cs_q[b * 256 + t] = s[t];
        float acc = mb[0];
        for (int j = 0; j < 64; j++) {
            int qi = t + j - 63;
            if (qi >= 0) acc += mw[j] * x[qi];
        }
        mc[b * 256 + t] = acc;
        if (t < QN) {
            float mn = s[t], mx = s[t];
            for (int j = 1; j < 64; j++) {
                float v = s[t + j];
                mn = fminf(mn, v); mx = fmaxf(mx, v);
            }
            float sc = mx - mn; if (sc == 0.f) sc = 1.f;
            q_off[b * QPAD + t] = mn;
            q_scale[b * QPAD + t] = sc;
        } else {
            q_off[b * QPAD + t] = 0.f;
            q_scale[b * QPAD + t] = 1.f;
        }
    } else {
        // ---- ref row (len 512): pair-scan ----
        int n = b - M_B;
        x[t] = r[n * 512 + t];
        x[t + 256] = r[n * 512 + t + 256];
        __syncthreads();
        P[t] = x[2 * t] + x[2 * t + 1];
        __syncthreads();
        for (int off = 1; off < 256; off <<= 1) {
            float v = (t >= off) ? P[t - off] : 0.f;
            __syncthreads();
            P[t] += v;
            __syncthreads();
        }
        s[2 * t + 1] = P[t];
        s[2 * t]     = P[t] - x[2 * t + 1];
        __syncthreads();
        cs_r[n * 512 + t] = s[t];
        cs_r[n * 512 + t + 256] = s[t + 256];
        for (int p = t; p < KPAD; p += 256) {
            if (p < KN) {
                float mn = s[p], mx = s[p];
                for (int j = 1; j < 64; j++) {
                    float v = s[p + j];
                    mn = fminf(mn, v); mx = fmaxf(mx, v);
                }
                float sc = mx - mn; if (sc == 0.f) sc = 1.f;
                k_off[n * KPAD + p] = mn;
                k_scale[n * KPAD + p] = sc;
            } else {
                k_off[n * KPAD + p] = 0.f;
                k_scale[n * KPAD + p] = 1.f;
            }
        }
    }
}

// ---------------- K1: q features -> fp32 qfeat + frag-major f16 hi/lo qg ----------------
// frag layout for 32-row waves: grp = (m*256+qpos)>>5; fb = (grp*8+c)*2+hilo
// addr = fb*512 + (kh*32 + (qpos&31))*8 + j5
__global__ void k1_qfeat(const float* __restrict__ cs_q, const float* __restrict__ q_off,
                         const float* __restrict__ q_scale,
                         const float* __restrict__ qw, const float* __restrict__ qb,
                         float* qfeat, _Float16* qg) {
    __shared__ float w[128 * 65];
    __shared__ float wsum[128];
    __shared__ float csS[80];
    __shared__ float offS[16], sclS[16];
    int m = blockIdx.x, chunk = blockIdx.y, t = threadIdx.x;
    int qbase = chunk * 16;
    for (int i = t; i < 8192; i += 256) {
        int h = i >> 6, j = i & 63;
        w[h * 65 + j] = qw[i];
    }
    if (t < 80) {
        int ci = qbase + t;
        csS[t] = (ci < 256) ? cs_q[m * 256 + ci] : 0.f;
    }
    if (t < 16) {
        int qpos = qbase + t;
        if (qpos < QN) { offS[t] = q_off[m * QPAD + qpos]; sclS[t] = q_scale[m * QPAD + qpos]; }
        else { offS[t] = 0.f; sclS[t] = 1.f; }
    }
    __syncthreads();
    if (t < 128) {
        float sm = 0.f;
        for (int j = 0; j < 64; j++) sm += w[t * 65 + j];
        wsum[t] = sm;
    }
    __syncthreads();
    int h = t & 127, ql0 = t >> 7;
    float bias = qb[h];
    int c = h >> 4, kh = (h >> 3) & 1, j5 = h & 7;
    for (int ql = ql0; ql < 16; ql += 2) {
        int qpos = qbase + ql;           // < 256 always
        float val = 0.f;
        if (qpos < QN) {
            float raw = 0.f;
            #pragma unroll 8
            for (int j = 0; j < 64; j++) raw += w[h * 65 + j] * csS[ql + j];
            val = (raw - offS[ql] * wsum[h]) / sclS[ql] + bias;
        }
        qfeat[((size_t)m * QPAD + qpos) * 128 + h] = val;
        _Float16 hi = (_Float16)val;
        _Float16 lo = (_Float16)((val - (float)hi) * 1024.0f);
        int grp = (m << 3) | (qpos >> 5);
        size_t fb = ((size_t)grp * 8 + c) * 2;
        size_t li = (size_t)(kh * 32 + (qpos & 31)) * 8 + j5;
        qg[fb * 512 + li] = hi;
        qg[(fb + 1) * 512 + li] = lo;
    }
}

// ---------------- K2: k/v features; weights in SGPRs, windows in VGPRs ----------------
// grid (64 n, 7 chunks of 64 kp), 256 thr: kl = t&63, hq = t>>6 owns 32 h.
__launch_bounds__(256, 3)
__global__ void k2_kv(const float* __restrict__ cs_r, const float* __restrict__ ref,
                      const float* __restrict__ k_off, const float* __restrict__ k_scale,
                      const float* __restrict__ kw, const float* __restrict__ kb,
                      const float* __restrict__ vw, const float* __restrict__ vb,
                      const float* __restrict__ wsum_k,
                      _Float16* __restrict__ kg, float* __restrict__ vfeat) {
    __shared__ float buf[128 * 65];          // [h][kl + pad]
    const int n = blockIdx.x, chunk = blockIdx.y, t = threadIdx.x;
    const int kl = t & 63, hq = t >> 6;
    const int kp = chunk * 64 + kl;
    const bool vkp = kp < KN;
    const float ko  = k_off[n * KPAD + kp];
    const float inv = 1.f / k_scale[n * KPAD + kp];

    // cumsum window (64 floats) in registers; coalesced per-j loads
    float csw[64];
    #pragma unroll 16
    for (int j = 0; j < 64; j++) csw[j] = cs_r[n * 512 + kp + j];

    // ---- phase 1: k features ----
    for (int hh = 0; hh < 32; hh++) {
        const int h = hq * 32 + hh;                 // wave-uniform
        const float* wrow = kw + h * 64;            // uniform -> s_load
        float a0 = 0.f, a1 = 0.f, a2 = 0.f, a3 = 0.f;
        #pragma unroll
        for (int j = 0; j < 64; j += 4) {
            a0 = fmaf(wrow[j],     csw[j],     a0);
            a1 = fmaf(wrow[j + 1], csw[j + 1], a1);
            a2 = fmaf(wrow[j + 2], csw[j + 2], a2);
            a3 = fmaf(wrow[j + 3], csw[j + 3], a3);
        }
        float kraw = (a0 + a1) + (a2 + a3);
        float kval = vkp ? (kraw - ko * wsum_k[h]) * inv + kb[h] : 0.f;
        buf[h * 65 + kl] = kval;
    }
    __syncthreads();
    // emit kg: 64 kp x 32 granules (16 hi + 16 lo), swizzled by kp&31
    {
        const size_t nb = ((size_t)n * KPAD + chunk * 64) * 256;
        #pragma unroll
        for (int r = 0; r < 8; r++) {
            int task = r * 256 + t;
            int kp_l = task >> 5, g = task & 31;
            int cb = g & 15, lo = g >> 4;
            half8 hv;
            #pragma unroll
            for (int jj = 0; jj < 8; jj++) {
                float v = buf[(cb * 8 + jj) * 65 + kp_l];
                _Float16 hi = (_Float16)v;
                hv[jj] = lo ? (_Float16)((v - (float)hi) * 1024.0f) : hi;
            }
            *(half8*)&kg[nb + (size_t)kp_l * 256 + ((size_t)(g ^ (kp_l & 31)) << 3)] = hv;
        }
    }
    __syncthreads();
    // ---- phase 2: v features ----
    float refw[32];
    #pragma unroll 8
    for (int j = 0; j < 32; j++) {
        int ri = 64 + kp + j;
        refw[j] = (ri < 512) ? ref[n * 512 + ri] : 0.f;
    }
    for (int hh = 0; hh < 32; hh++) {
        const int h = hq * 32 + hh;
        const float* vrow = vw + h * 32;            // uniform -> s_load
        float b0 = 0.f, b1 = 0.f;
        #pragma unroll
        for (int j = 0; j < 32; j += 2) {
            b0 = fmaf(vrow[j],     refw[j],     b0);
            b1 = fmaf(vrow[j + 1], refw[j + 1], b1);
        }
        float vval = vkp ? (b0 + b1) * inv + vb[h] : 0.f;
        buf[h * 65 + kl] = vval;
    }
    __syncthreads();
    {
        const size_t vb0 = ((size_t)n * KPAD + chunk * 64) * 128;
        #pragma unroll
        for (int r = 0; r < 8; r++) {
            int idx = r * 256 + t;
            int kp_l = idx >> 5, c4 = idx & 31;
            float4 o;
            o.x = buf[(c4 * 4 + 0) * 65 + kp_l];
            o.y = buf[(c4 * 4 + 1) * 65 + kp_l];
            o.z = buf[(c4 * 4 + 2) * 65 + kp_l];
            o.w = buf[(c4 * 4 + 3) * 65 + kp_l];
            *(float4*)&vfeat[vb0 + (size_t)kp_l * 128 + c4 * 4] = o;
        }
    }
}

// ---------------- K3: split-f16 MFMA score matmul + max/argmax ----------------
// 32 q-rows per wave, 4 waves/block (128 rows), grid 16 qt x 64 n = 1024 blocks.
// K staged 32 kpos/chunk, double-buffered via global_load_lds; XOR-swizzled.
__launch_bounds__(256, 3)
__global__ void k3_score(const _Float16* __restrict__ qg, const _Float16* __restrict__ kg,
                         float* __restrict__ bscore, int* __restrict__ bidx) {
    __shared__ _Float16 Kbuf[2][32 * 256];   // 16 KB each
    const int blk = blockIdx.x;
    const int n = blk & 63, qt = blk >> 6;
    const int t = threadIdx.x, w = t >> 6, l = t & 63;
    const int lrow = l & 31, khalf = l >> 5;
    const int grp = qt * 4 + w;              // 32-row group id (0..63)

    half8 qf[8][2];
    {
        const half8* qb = (const half8*)qg + (size_t)grp * 16 * 64 + l;
        #pragma unroll
        for (int c = 0; c < 8; c++)
            #pragma unroll
            for (int h = 0; h < 2; h++)
                qf[c][h] = qb[(c * 2 + h) * 64];
    }

    const _Float16* ksrc = kg + (size_t)n * KPAD * 256;

    float best[16];
    unsigned bkt0 = 0u, bkt1 = 0u;
    #pragma unroll
    for (int g = 0; g < 16; g++) best[g] = -INFINITY;

    #pragma unroll
    for (int rd = 0; rd < 4; rd++) {
        int e = (rd * 4 + w) * 512 + l * 8;
        GLOAD_LDS16(ksrc + e, &Kbuf[0][0] + e);
    }

    #pragma unroll
    for (int kt = 0; kt < 14; kt++) {
        __syncthreads();                       // staged chunk kt ready
        if (kt < 13) {
            const _Float16* src = ksrc + (size_t)(kt + 1) * (32 * 256);
            _Float16* dst = &Kbuf[(kt + 1) & 1][0];
            #pragma unroll
            for (int rd = 0; rd < 4; rd++) {
                int e = (rd * 4 + w) * 512 + l * 8;
                GLOAD_LDS16(src + e, dst + e);
            }
        }
        const _Float16* kb = &Kbuf[kt & 1][0];
        f32x16 accH = zero16(), accL = zero16();
        #pragma unroll
        for (int c = 0; c < 8; c++) {
            half8 bh = *(const half8*)(kb + lrow * 256 + (((c * 2 + khalf) ^ lrow) * 8));
            half8 bl = *(const half8*)(kb + lrow * 256 + (((16 + c * 2 + khalf) ^ lrow) * 8));
            accH = mfma_f16(qf[c][0], bh, accH);
            accL = mfma_f16(qf[c][0], bl, accL);
            accL = mfma_f16(qf[c][1], bh, accL);
        }
        const int kp = kt * 32 + lrow;
        const bool valid = kp < KN;
        #pragma unroll
        for (int g = 0; g < 16; g++) {
            float s = fmaf(accL[g], 0.0009765625f, accH[g]);
            bool upd = valid && (s > best[g]);
            best[g] = upd ? s : best[g];
            if (g < 8) {
                unsigned nb = (bkt0 & ~(0xFu << (4 * g))) | ((unsigned)kt << (4 * g));
                bkt0 = upd ? nb : bkt0;
            } else {
                unsigned nb = (bkt1 & ~(0xFu << (4 * (g - 8)))) | ((unsigned)kt << (4 * (g - 8)));
                bkt1 = upd ? nb : bkt1;
            }
        }
    }

    // cross-lane argmax reduce within each 32-lane half
    #pragma unroll
    for (int g = 0; g < 16; g++) {
        float s = best[g];
        int ktb = (g < 8) ? (int)((bkt0 >> (4 * g)) & 0xFu)
                          : (int)((bkt1 >> (4 * (g - 8))) & 0xFu);
        int kp = ktb * 32 + lrow;
        for (int msk = 1; msk < 32; msk <<= 1) {
            float os = __shfl_xor(s, msk, 64);
            int okp = __shfl_xor(kp, msk, 64);
            if (os > s || (os == s && okp < kp)) { s = os; kp = okp; }
        }
        if (lrow == 0) {
            int row = (g & 3) + 8 * (g >> 2) + 4 * khalf;
            int mq = grp * 32 + row;
            if ((mq & 255) < QN) {
                bscore[(size_t)mq * 64 + n] = s;
                bidx[(size_t)mq * 64 + n] = kp;
            }
        }
    }
}

// ---------------- K4: one wave per qpos: softmax + gather-weight V + projection ----------------
// grid 386 blocks x 256 thr (4 waves); 386*4 == 1544 exactly.
__global__ void k4_out(const float* __restrict__ qfeat, const float* __restrict__ vfeat,
                       const float* __restrict__ bscore, const int* __restrict__ bidx,
                       const float* __restrict__ q_scale, const float* __restrict__ mc,
                       const float* __restrict__ mkey,
                       const float* __restrict__ ow, const float* __restrict__ ob,
                       float* __restrict__ out) {
    __shared__ float rsS[4][64];
    __shared__ int   idxS[4][64];
    __shared__ float wS[4][128];
    const int t = threadIdx.x, wv = t >> 6, l = t & 63;
    const int j = blockIdx.x * 4 + wv;       // 0..1543
    const int m = j / QN, qpos = j - m * QN;
    const int mq = m * QPAD + qpos;

    float s = bscore[(size_t)mq * 64 + l];
    int idx = bidx[(size_t)mq * 64 + l];
    float msv = qfeat[(size_t)mq * 128 + l] * mkey[l]
              + qfeat[(size_t)mq * 128 + 64 + l] * mkey[64 + l];
    #pragma unroll
    for (int msk = 1; msk < 64; msk <<= 1) msv += __shfl_xor(msv, msk, 64);
    float mx = s;
    #pragma unroll
    for (int msk = 1; msk < 64; msk <<= 1) mx = fmaxf(mx, __shfl_xor(mx, msk, 64));
    mx = fmaxf(mx, msv);
    float e = expf(s - mx);
    float sum = e;
    #pragma unroll
    for (int msk = 1; msk < 64; msk <<= 1) sum += __shfl_xor(sum, msk, 64);
    float ems = expf(msv - mx);
    float inv = 1.f / (sum + ems);
    float rs = e * inv, msw = ems * inv;

    rsS[wv][l] = rs; idxS[wv][l] = idx;
    __syncthreads();
    float ax = 0.f, ay = 0.f;
    #pragma unroll 8
    for (int nn = 0; nn < 64; nn++) {
        float r = rsS[wv][nn];
        int id = idxS[wv][nn];
        const float2 v = *(const float2*)&vfeat[((size_t)nn * KPAD + id) * 128 + 2 * l];
        ax = fmaf(r, v.x, ax);
        ay = fmaf(r, v.y, ay);
    }
    wS[wv][2 * l] = ax; wS[wv][2 * l + 1] = ay;
    __syncthreads();
    if (l < 32) {
        float p = 0.f;
        #pragma unroll
        for (int h4 = 0; h4 < 32; h4++) {
            const float4 wv4 = *(const float4*)&wS[wv][h4 * 4];
            const float4 o4 = *(const float4*)&ow[l * 128 + h4 * 4];
            p += wv4.x * o4.x + wv4.y * o4.y + wv4.z * o4.z + wv4.w * o4.w;
        }
        p += (1.f - msw) * ob[l];
        float outv = q_scale[mq] * p + msw * mc[m * 256 + 32 + qpos + l];
        out[(size_t)j * 32 + l] = outv;
    }
}

extern "C" void kernel_launch(void* const* d_in, const int* in_sizes, int n_in,
                              void* d_out, int out_size, void* d_ws, size_t ws_size,
                              hipStream_t stream) {
    const float* query = (const float*)d_in[0];
    const float* ref   = (const float*)d_in[1];
    const float* qw    = (const float*)d_in[2];
    const float* qb    = (const float*)d_in[3];
    const float* kw    = (const float*)d_in[4];
    const float* kb    = (const float*)d_in[5];
    const float* vw    = (const float*)d_in[6];
    const float* vb    = (const float*)d_in[7];
    const float* mw    = (const float*)d_in[8];
    const float* mb    = (const float*)d_in[9];
    const float* ow    = (const float*)d_in[10];
    const float* ob    = (const float*)d_in[11];
    const float* mkey  = (const float*)d_in[12];
    float* out = (float*)d_out;

    // workspace layout (floats) — all segments 16B-aligned
    float* ws = (float*)d_ws;
    float* cs_q    = ws;                        // 2048
    float* cs_r    = cs_q + 2048;               // 32768
    float* mc      = cs_r + 32768;              // 2048
    float* q_off   = mc + 2048;                 // 2048
    float* q_scale = q_off + 2048;              // 2048
    float* k_off   = q_scale + 2048;            // 28672
    float* k_scale = k_off + 28672;             // 28672  -> 98304
    float* qfeat   = k_scale + 28672;           // 262144 -> 360448
    float* bscore  = qfeat + 262144;            // 131072 -> 491520
    int*   bidx    = (int*)(bscore + 131072);   // 131072 -> 622592
    float* wsum_k  = bscore + 262144;           // 128    -> 622720
    _Float16* qg   = (_Float16*)(wsum_k + 128);           // 524288 halfs = 262144 fl -> 884864
    _Float16* kg   = (_Float16*)(wsum_k + 128 + 262144);  // 7340032 halfs = 3670016 fl -> 4554880
    float* vfeat   = wsum_k + 128 + 262144 + 3670016;     // 3670016 fl -> 8224896

    hipLaunchKernelGGL(k0_scan, dim3(M_B + N_B + 1), dim3(256), 0, stream,
                       query, ref, cs_q, cs_r, mc, q_off, q_scale, k_off, k_scale,
                       mw, mb, kw, wsum_k);
    hipLaunchKernelGGL(k1_qfeat, dim3(8, 16), dim3(256), 0, stream,
                       cs_q, q_off, q_scale, qw, qb, qfeat, qg);
    hipLaunchKernelGGL(k2_kv, dim3(64, 7), dim3(256), 0, stream,
                       cs_r, ref, k_off, k_scale, kw, kb, vw, vb, wsum_k, kg, vfeat);
    hipLaunchKernelGGL(k3_score, dim3(1024), dim3(256), 0, stream,
                       qg, kg, bscore, bidx);
    hipLaunchKernelGGL(k4_out, dim3(386), dim3(256), 0, stream,
                       qfeat, vfeat, bscore, bidx, q_scale, mc, mkey, ow, ob, out);
}

// Round 4
// 266.029 us; speedup vs baseline: 1.5006x; 1.5006x over previous
//
#include <hip/hip_runtime.h>
#include <cmath>

// Problem constants
#define M_B   8
#define LQ    256
#define N_B   64
#define LR    512
#define COND  64
#define PRED  32
#define DH    128
#define QN    193      // LQ-COND+1
#define KN    417      // (LR-PRED)-COND+1
#define QPAD  256      // per-m padded q rows (8*256 = 2048 total)
#define KPAD  448      // padded kpos (14 chunks of 32)

typedef _Float16 half8 __attribute__((ext_vector_type(8)));
typedef float f32x16 __attribute__((ext_vector_type(16)));

__device__ __forceinline__ f32x16 mfma_f16(half8 a, half8 b, f32x16 c) {
    return __builtin_amdgcn_mfma_f32_32x32x16_f16(a, b, c, 0, 0, 0);
}
__device__ __forceinline__ f32x16 zero16() {
    f32x16 z;
    #pragma unroll
    for (int i = 0; i < 16; i++) z[i] = 0.f;
    return z;
}

#define GLOAD_LDS16(g, l) __builtin_amdgcn_global_load_lds( \
    (const __attribute__((address_space(1))) void*)(g), \
    (__attribute__((address_space(3))) void*)(l), 16, 0, 0)

// ---------------- K0: cumsums, minmax offsets/scales, mc, wsum_k/wsum_q ----------------
__global__ void k0_scan(const float* __restrict__ q, const float* __restrict__ r,
                        float* cs_q, float* cs_r, float* mc,
                        float* q_off, float* q_scale, float* k_off, float* k_scale,
                        const float* __restrict__ mw, const float* __restrict__ mb,
                        const float* __restrict__ kw, const float* __restrict__ qwg,
                        float* wsum_k, float* wsum_q) {
    __shared__ float x[512];
    __shared__ float s[512];
    __shared__ float P[256];
    int b = blockIdx.x, t = threadIdx.x;
    if (b == M_B + N_B) {
        if (t < 128) {
            float sk = 0.f, sq = 0.f;
            for (int j = 0; j < 64; j++) { sk += kw[t * 64 + j]; sq += qwg[t * 64 + j]; }
            wsum_k[t] = sk;
            wsum_q[t] = sq;
        }
        return;
    }
    if (b < M_B) {
        // ---- query row b (len 256) ----
        x[t] = q[b * 256 + t];
        __syncthreads();
        s[t] = x[t];
        __syncthreads();
        for (int off = 1; off < 256; off <<= 1) {
            float v = (t >= off) ? s[t - off] : 0.f;
            __syncthreads();
            s[t] += v;
            __syncthreads();
        }
        cs_q[b * 256 + t] = s[t];
        float acc = mb[0];
        for (int j = 0; j < 64; j++) {
            int qi = t + j - 63;
            if (qi >= 0) acc += mw[j] * x[qi];
        }
        mc[b * 256 + t] = acc;
        if (t < QN) {
            float mn = s[t], mx = s[t];
            for (int j = 1; j < 64; j++) {
                float v = s[t + j];
                mn = fminf(mn, v); mx = fmaxf(mx, v);
            }
            float sc = mx - mn; if (sc == 0.f) sc = 1.f;
            q_off[b * QPAD + t] = mn;
            q_scale[b * QPAD + t] = sc;
        } else {
            q_off[b * QPAD + t] = 0.f;
            q_scale[b * QPAD + t] = 1.f;
        }
    } else {
        // ---- ref row (len 512): pair-scan ----
        int n = b - M_B;
        x[t] = r[n * 512 + t];
        x[t + 256] = r[n * 512 + t + 256];
        __syncthreads();
        P[t] = x[2 * t] + x[2 * t + 1];
        __syncthreads();
        for (int off = 1; off < 256; off <<= 1) {
            float v = (t >= off) ? P[t - off] : 0.f;
            __syncthreads();
            P[t] += v;
            __syncthreads();
        }
        s[2 * t + 1] = P[t];
        s[2 * t]     = P[t] - x[2 * t + 1];
        __syncthreads();
        cs_r[n * 512 + t] = s[t];
        cs_r[n * 512 + t + 256] = s[t + 256];
        for (int p = t; p < KPAD; p += 256) {
            if (p < KN) {
                float mn = s[p], mx = s[p];
                for (int j = 1; j < 64; j++) {
                    float v = s[p + j];
                    mn = fminf(mn, v); mx = fmaxf(mx, v);
                }
                float sc = mx - mn; if (sc == 0.f) sc = 1.f;
                k_off[n * KPAD + p] = mn;
                k_scale[n * KPAD + p] = sc;
            } else {
                k_off[n * KPAD + p] = 0.f;
                k_scale[n * KPAD + p] = 1.f;
            }
        }
    }
}

// ---------------- K1: q features; scalar weights (readfirstlane), lanes = qpos ----------------
// grid (8 m, 4 qchunk of 64), 256 thr: wave hq owns 32 h, lane ql -> qpos.
__launch_bounds__(256, 2)
__global__ void k1_qfeat(const float* __restrict__ cs_q, const float* __restrict__ q_off,
                         const float* __restrict__ q_scale,
                         const float* __restrict__ qw, const float* __restrict__ qb,
                         const float* __restrict__ wsum_q,
                         float* __restrict__ qfeat, _Float16* __restrict__ qg) {
    __shared__ float buf[128 * 65];          // [h][ql + pad]
    const int m = blockIdx.x, qc = blockIdx.y, t = threadIdx.x;
    const int ql = t & 63;
    const int hq = __builtin_amdgcn_readfirstlane(t >> 6);
    const int qpos = qc * 64 + ql;           // 0..255
    const bool vq = qpos < QN;
    const float off = q_off[m * QPAD + qpos];
    const float inv = 1.f / q_scale[m * QPAD + qpos];
    const int base = vq ? qpos : (QN - 1);   // keep reads in-range for pad rows
    float csw[64];
    #pragma unroll 16
    for (int j = 0; j < 64; j++) csw[j] = cs_q[m * 256 + base + j];

    for (int hh = 0; hh < 32; hh++) {
        const int h = hq * 32 + hh;          // wave-uniform -> s_load weights
        const float* wrow = qw + h * 64;
        float a0 = 0.f, a1 = 0.f, a2 = 0.f, a3 = 0.f;
        #pragma unroll
        for (int j = 0; j < 64; j += 4) {
            a0 = fmaf(wrow[j],     csw[j],     a0);
            a1 = fmaf(wrow[j + 1], csw[j + 1], a1);
            a2 = fmaf(wrow[j + 2], csw[j + 2], a2);
            a3 = fmaf(wrow[j + 3], csw[j + 3], a3);
        }
        float raw = (a0 + a1) + (a2 + a3);
        float val = vq ? (raw - off * wsum_q[h]) * inv + qb[h] : 0.f;
        buf[h * 65 + ql] = val;
    }
    __syncthreads();
    // emit qfeat (coalesced float4)
    const size_t qb0 = ((size_t)m * QPAD + qc * 64) * 128;
    #pragma unroll
    for (int r = 0; r < 8; r++) {
        int idx = r * 256 + t;
        int qp_l = idx >> 5, c4 = idx & 31;
        float4 o;
        o.x = buf[(c4 * 4 + 0) * 65 + qp_l];
        o.y = buf[(c4 * 4 + 1) * 65 + qp_l];
        o.z = buf[(c4 * 4 + 2) * 65 + qp_l];
        o.w = buf[(c4 * 4 + 3) * 65 + qp_l];
        *(float4*)&qfeat[qb0 + (size_t)qp_l * 128 + c4 * 4] = o;
    }
    // emit qg frag-major hi/lo: h = c*16 + kh*8 + j5; fb = grp*16 + c*2 + lo
    #pragma unroll
    for (int r = 0; r < 8; r++) {
        int idx = r * 256 + t;
        int qp_l = idx >> 5, g = idx & 31;
        int c = g >> 2, kh = (g >> 1) & 1, lo = g & 1;
        half8 hv;
        #pragma unroll
        for (int jj = 0; jj < 8; jj++) {
            float v = buf[(c * 16 + kh * 8 + jj) * 65 + qp_l];
            _Float16 hi = (_Float16)v;
            hv[jj] = lo ? (_Float16)((v - (float)hi) * 1024.0f) : hi;
        }
        int qp2 = qc * 64 + qp_l;
        int grp = (m << 3) | (qp2 >> 5);
        size_t fb = (size_t)(grp * 16 + c * 2 + lo);
        *(half8*)&qg[fb * 512 + (size_t)(kh * 32 + (qp2 & 31)) * 8] = hv;
    }
}

// ---------------- K2: k/v features; scalar weights, windows in VGPRs ----------------
// grid (64 n, 7 chunks of 64 kp), 256 thr: kl = t&63, wave hq owns 32 h.
__launch_bounds__(256, 2)
__global__ void k2_kv(const float* __restrict__ cs_r, const float* __restrict__ ref,
                      const float* __restrict__ k_off, const float* __restrict__ k_scale,
                      const float* __restrict__ kw, const float* __restrict__ kb,
                      const float* __restrict__ vw, const float* __restrict__ vb,
                      const float* __restrict__ wsum_k,
                      _Float16* __restrict__ kg, float* __restrict__ vfeat) {
    __shared__ float buf[128 * 65];          // [h][kl + pad]
    const int n = blockIdx.x, chunk = blockIdx.y, t = threadIdx.x;
    const int kl = t & 63;
    const int hq = __builtin_amdgcn_readfirstlane(t >> 6);
    const int kp = chunk * 64 + kl;
    const bool vkp = kp < KN;
    const float ko  = k_off[n * KPAD + kp];
    const float inv = 1.f / k_scale[n * KPAD + kp];

    float csw[64];
    #pragma unroll 16
    for (int j = 0; j < 64; j++) csw[j] = cs_r[n * 512 + kp + j];

    // ---- phase 1: k features ----
    for (int hh = 0; hh < 32; hh++) {
        const int h = hq * 32 + hh;          // wave-uniform -> s_load weights
        const float* wrow = kw + h * 64;
        float a0 = 0.f, a1 = 0.f, a2 = 0.f, a3 = 0.f;
        #pragma unroll
        for (int j = 0; j < 64; j += 4) {
            a0 = fmaf(wrow[j],     csw[j],     a0);
            a1 = fmaf(wrow[j + 1], csw[j + 1], a1);
            a2 = fmaf(wrow[j + 2], csw[j + 2], a2);
            a3 = fmaf(wrow[j + 3], csw[j + 3], a3);
        }
        float kraw = (a0 + a1) + (a2 + a3);
        float kval = vkp ? (kraw - ko * wsum_k[h]) * inv + kb[h] : 0.f;
        buf[h * 65 + kl] = kval;
    }
    __syncthreads();
    // emit kg: 64 kp x 32 granules (16 hi + 16 lo), swizzled by kp&31
    {
        const size_t nb = ((size_t)n * KPAD + chunk * 64) * 256;
        #pragma unroll
        for (int r = 0; r < 8; r++) {
            int task = r * 256 + t;
            int kp_l = task >> 5, g = task & 31;
            int cb = g & 15, lo = g >> 4;
            half8 hv;
            #pragma unroll
            for (int jj = 0; jj < 8; jj++) {
                float v = buf[(cb * 8 + jj) * 65 + kp_l];
                _Float16 hi = (_Float16)v;
                hv[jj] = lo ? (_Float16)((v - (float)hi) * 1024.0f) : hi;
            }
            *(half8*)&kg[nb + (size_t)kp_l * 256 + ((size_t)(g ^ (kp_l & 31)) << 3)] = hv;
        }
    }
    __syncthreads();
    // ---- phase 2: v features ----
    float refw[32];
    #pragma unroll 8
    for (int j = 0; j < 32; j++) {
        int ri = 64 + kp + j;
        refw[j] = (ri < 512) ? ref[n * 512 + ri] : 0.f;
    }
    for (int hh = 0; hh < 32; hh++) {
        const int h = hq * 32 + hh;
        const float* vrow = vw + h * 32;
        float b0 = 0.f, b1 = 0.f;
        #pragma unroll
        for (int j = 0; j < 32; j += 2) {
            b0 = fmaf(vrow[j],     refw[j],     b0);
            b1 = fmaf(vrow[j + 1], refw[j + 1], b1);
        }
        float vval = vkp ? (b0 + b1) * inv + vb[h] : 0.f;
        buf[h * 65 + kl] = vval;
    }
    __syncthreads();
    {
        const size_t vb0 = ((size_t)n * KPAD + chunk * 64) * 128;
        #pragma unroll
        for (int r = 0; r < 8; r++) {
            int idx = r * 256 + t;
            int kp_l = idx >> 5, c4 = idx & 31;
            float4 o;
            o.x = buf[(c4 * 4 + 0) * 65 + kp_l];
            o.y = buf[(c4 * 4 + 1) * 65 + kp_l];
            o.z = buf[(c4 * 4 + 2) * 65 + kp_l];
            o.w = buf[(c4 * 4 + 3) * 65 + kp_l];
            *(float4*)&vfeat[vb0 + (size_t)kp_l * 128 + c4 * 4] = o;
        }
    }
}

// ---------------- K3: split-f16 MFMA score matmul + max/argmax ----------------
// 32 q-rows per wave, 4 waves/block, grid 16 qt x 64 n = 1024 blocks.
// K staged 32 kpos/chunk, double-buffered via global_load_lds; XOR-swizzled.
__launch_bounds__(256, 2)
__global__ void k3_score(const _Float16* __restrict__ qg, const _Float16* __restrict__ kg,
                         float* __restrict__ bscore, int* __restrict__ bidx) {
    __shared__ _Float16 Kbuf[2][32 * 256];   // 16 KB each
    const int blk = blockIdx.x;
    const int n = blk & 63, qt = blk >> 6;
    const int t = threadIdx.x, w = t >> 6, l = t & 63;
    const int lrow = l & 31, khalf = l >> 5;
    const int grp = qt * 4 + w;              // 32-row group id (0..63)

    half8 qf[8][2];
    {
        const half8* qb = (const half8*)qg + (size_t)grp * 16 * 64 + l;
        #pragma unroll
        for (int c = 0; c < 8; c++)
            #pragma unroll
            for (int h = 0; h < 2; h++)
                qf[c][h] = qb[(c * 2 + h) * 64];
    }

    const _Float16* ksrc = kg + (size_t)n * KPAD * 256;

    float best[16];
    unsigned bkt0 = 0u, bkt1 = 0u;
    #pragma unroll
    for (int g = 0; g < 16; g++) best[g] = -INFINITY;

    #pragma unroll
    for (int rd = 0; rd < 4; rd++) {
        int e = (rd * 4 + w) * 512 + l * 8;
        GLOAD_LDS16(ksrc + e, &Kbuf[0][0] + e);
    }

    for (int kt = 0; kt < 14; kt++) {
        __syncthreads();                       // staged chunk kt ready
        if (kt < 13) {
            const _Float16* src = ksrc + (size_t)(kt + 1) * (32 * 256);
            _Float16* dst = &Kbuf[(kt + 1) & 1][0];
            #pragma unroll
            for (int rd = 0; rd < 4; rd++) {
                int e = (rd * 4 + w) * 512 + l * 8;
                GLOAD_LDS16(src + e, dst + e);
            }
        }
        const _Float16* kb = &Kbuf[kt & 1][0];
        f32x16 accH = zero16(), accL = zero16();
        #pragma unroll
        for (int c = 0; c < 8; c++) {
            half8 bh = *(const half8*)(kb + lrow * 256 + (((c * 2 + khalf) ^ lrow) * 8));
            half8 bl = *(const half8*)(kb + lrow * 256 + (((16 + c * 2 + khalf) ^ lrow) * 8));
            accH = mfma_f16(qf[c][0], bh, accH);
            accL = mfma_f16(qf[c][0], bl, accL);
            accL = mfma_f16(qf[c][1], bh, accL);
        }
        const int kp = kt * 32 + lrow;
        const bool valid = kp < KN;
        #pragma unroll
        for (int g = 0; g < 16; g++) {
            float s = fmaf(accL[g], 0.0009765625f, accH[g]);
            bool upd = valid && (s > best[g]);
            best[g] = upd ? s : best[g];
            if (g < 8) {
                unsigned nb = (bkt0 & ~(0xFu << (4 * g))) | ((unsigned)kt << (4 * g));
                bkt0 = upd ? nb : bkt0;
            } else {
                unsigned nb = (bkt1 & ~(0xFu << (4 * (g - 8)))) | ((unsigned)kt << (4 * (g - 8)));
                bkt1 = upd ? nb : bkt1;
            }
        }
    }

    // cross-lane argmax reduce within each 32-lane half
    #pragma unroll
    for (int g = 0; g < 16; g++) {
        float s = best[g];
        int ktb = (g < 8) ? (int)((bkt0 >> (4 * g)) & 0xFu)
                          : (int)((bkt1 >> (4 * (g - 8))) & 0xFu);
        int kp = ktb * 32 + lrow;
        for (int msk = 1; msk < 32; msk <<= 1) {
            float os = __shfl_xor(s, msk, 64);
            int okp = __shfl_xor(kp, msk, 64);
            if (os > s || (os == s && okp < kp)) { s = os; kp = okp; }
        }
        if (lrow == 0) {
            int row = (g & 3) + 8 * (g >> 2) + 4 * khalf;
            int mq = grp * 32 + row;
            if ((mq & 255) < QN) {
                bscore[(size_t)mq * 64 + n] = s;
                bidx[(size_t)mq * 64 + n] = kp;
            }
        }
    }
}

// ---------------- K4: one wave per qpos: softmax + gather-weight V + projection ----------------
__global__ void k4_out(const float* __restrict__ qfeat, const float* __restrict__ vfeat,
                       const float* __restrict__ bscore, const int* __restrict__ bidx,
                       const float* __restrict__ q_scale, const float* __restrict__ mc,
                       const float* __restrict__ mkey,
                       const float* __restrict__ ow, const float* __restrict__ ob,
                       float* __restrict__ out) {
    __shared__ float rsS[4][64];
    __shared__ int   idxS[4][64];
    __shared__ float wS[4][128];
    const int t = threadIdx.x, wv = t >> 6, l = t & 63;
    const int j = blockIdx.x * 4 + wv;       // 0..1543
    const int m = j / QN, qpos = j - m * QN;
    const int mq = m * QPAD + qpos;

    float s = bscore[(size_t)mq * 64 + l];
    int idx = bidx[(size_t)mq * 64 + l];
    float msv = qfeat[(size_t)mq * 128 + l] * mkey[l]
              + qfeat[(size_t)mq * 128 + 64 + l] * mkey[64 + l];
    #pragma unroll
    for (int msk = 1; msk < 64; msk <<= 1) msv += __shfl_xor(msv, msk, 64);
    float mx = s;
    #pragma unroll
    for (int msk = 1; msk < 64; msk <<= 1) mx = fmaxf(mx, __shfl_xor(mx, msk, 64));
    mx = fmaxf(mx, msv);
    float e = expf(s - mx);
    float sum = e;
    #pragma unroll
    for (int msk = 1; msk < 64; msk <<= 1) sum += __shfl_xor(sum, msk, 64);
    float ems = expf(msv - mx);
    float inv = 1.f / (sum + ems);
    float rs = e * inv, msw = ems * inv;

    rsS[wv][l] = rs; idxS[wv][l] = idx;
    __syncthreads();
    float ax = 0.f, ay = 0.f;
    #pragma unroll 8
    for (int nn = 0; nn < 64; nn++) {
        float r = rsS[wv][nn];
        int id = idxS[wv][nn];
        const float2 v = *(const float2*)&vfeat[((size_t)nn * KPAD + id) * 128 + 2 * l];
        ax = fmaf(r, v.x, ax);
        ay = fmaf(r, v.y, ay);
    }
    wS[wv][2 * l] = ax; wS[wv][2 * l + 1] = ay;
    __syncthreads();
    if (l < 32) {
        float p = 0.f;
        #pragma unroll
        for (int h4 = 0; h4 < 32; h4++) {
            const float4 wv4 = *(const float4*)&wS[wv][h4 * 4];
            const float4 o4 = *(const float4*)&ow[l * 128 + h4 * 4];
            p += wv4.x * o4.x + wv4.y * o4.y + wv4.z * o4.z + wv4.w * o4.w;
        }
        p += (1.f - msw) * ob[l];
        float outv = q_scale[mq] * p + msw * mc[m * 256 + 32 + qpos + l];
        out[(size_t)j * 32 + l] = outv;
    }
}

extern "C" void kernel_launch(void* const* d_in, const int* in_sizes, int n_in,
                              void* d_out, int out_size, void* d_ws, size_t ws_size,
                              hipStream_t stream) {
    const float* query = (const float*)d_in[0];
    const float* ref   = (const float*)d_in[1];
    const float* qw    = (const float*)d_in[2];
    const float* qb    = (const float*)d_in[3];
    const float* kw    = (const float*)d_in[4];
    const float* kb    = (const float*)d_in[5];
    const float* vw    = (const float*)d_in[6];
    const float* vb    = (const float*)d_in[7];
    const float* mw    = (const float*)d_in[8];
    const float* mb    = (const float*)d_in[9];
    const float* ow    = (const float*)d_in[10];
    const float* ob    = (const float*)d_in[11];
    const float* mkey  = (const float*)d_in[12];
    float* out = (float*)d_out;

    // workspace layout (floats) — all segments 16B-aligned
    float* ws = (float*)d_ws;
    float* cs_q    = ws;                        // 2048
    float* cs_r    = cs_q + 2048;               // 32768 -> 34816
    float* mc      = cs_r + 32768;              // 2048  -> 36864
    float* q_off   = mc + 2048;                 // 2048  -> 38912
    float* q_scale = q_off + 2048;              // 2048  -> 40960
    float* k_off   = q_scale + 2048;            // 28672 -> 69632
    float* k_scale = k_off + 28672;             // 28672 -> 98304
    float* qfeat   = k_scale + 28672;           // 262144 -> 360448
    float* bscore  = qfeat + 262144;            // 131072 -> 491520
    int*   bidx    = (int*)(bscore + 131072);   // 131072 -> 622592
    float* wsum_k  = bscore + 262144;           // 128 -> 622720
    float* wsum_q  = wsum_k + 128;              // 128 -> 622848
    _Float16* qg   = (_Float16*)(wsum_q + 128);           // 524288 halfs -> 884992
    _Float16* kg   = (_Float16*)(wsum_q + 128 + 262144);  // 7340032 halfs -> 4555008
    float* vfeat   = wsum_q + 128 + 262144 + 3670016;     // 3670016 fl -> 8225024

    hipLaunchKernelGGL(k0_scan, dim3(M_B + N_B + 1), dim3(256), 0, stream,
                       query, ref, cs_q, cs_r, mc, q_off, q_scale, k_off, k_scale,
                       mw, mb, kw, qw, wsum_k, wsum_q);
    hipLaunchKernelGGL(k1_qfeat, dim3(8, 4), dim3(256), 0, stream,
                       cs_q, q_off, q_scale, qw, qb, wsum_q, qfeat, qg);
    hipLaunchKernelGGL(k2_kv, dim3(64, 7), dim3(256), 0, stream,
                       cs_r, ref, k_off, k_scale, kw, kb, vw, vb, wsum_k, kg, vfeat);
    hipLaunchKernelGGL(k3_score, dim3(1024), dim3(256), 0, stream,
                       qg, kg, bscore, bidx);
    hipLaunchKernelGGL(k4_out, dim3(386), dim3(256), 0, stream,
                       qfeat, vfeat, bscore, bidx, q_scale, mc, mkey, ow, ob, out);
}